// Round 7
// baseline (991.650 us; speedup 1.0000x reference)
//
#include <hip/hip_runtime.h>
#include <hip/hip_cooperative_groups.h>
#include <math.h>

namespace cg = cooperative_groups;

// Problem constants
#define B_   64
#define L_   577
#define D_   512
#define E_   1024
#define H_   512
#define K_   288            // selected tokens per batch
#define N_   (B_ * K_)      // 18432 total rows
#define KBIG 1024           // concatenated K for fused GEMM2
#define MTILES (N_ / 128)   // 144
#define GRID_ 576           // = MTILES*4 GEMM1 tiles; needs only 3 blocks/CU
#define NTHREADS (GRID_ * 256)

typedef __attribute__((ext_vector_type(8))) __bf16 bf16x8;
typedef __attribute__((ext_vector_type(4))) float f32x4;
typedef __attribute__((ext_vector_type(4))) unsigned short ushort4v;
typedef __attribute__((ext_vector_type(8))) unsigned short ushort8v;

// ---------------- workspace layout (bytes) ----------------
#define OFF_WBIG    0                    // 1024*1024 bf16 = 2,097,152
#define OFF_W0B     2097152              // 512*512 bf16   =   524,288
#define OFF_BIASBIG 2621440              // 1024 f32
#define OFF_SCSH    2625536              // 1024 f32 (sc, sh)
#define OFF_IDX     2629632              // 18432 i32 = 73,728
#define OFF_PSUM    2703360              // 512 f32 (atomic totals)
#define OFF_PSQ     2705408              // 512 f32
#define OFF_OUTENC  2707456              // 64*1024 u32 = 262,144
#define OFF_ABIG    2969600              // N*1024 bf16 = 37,748,736

static __device__ __forceinline__ unsigned short f2bf(float f) {
  unsigned int u = __builtin_bit_cast(unsigned int, f);
  u = (u + 0x7fffu + ((u >> 16) & 1u)) >> 16;
  return (unsigned short)u;
}
static __device__ __forceinline__ float bf2f(unsigned short s) {
  unsigned int u = ((unsigned int)s) << 16;
  return __builtin_bit_cast(float, u);
}
// monotone fp32 <-> uint encoding for atomicMax on floats
static __device__ __forceinline__ unsigned int encf(float f) {
  unsigned int u = __builtin_bit_cast(unsigned int, f);
  return (u & 0x80000000u) ? ~u : (u | 0x80000000u);
}
static __device__ __forceinline__ float decf(unsigned int e) {
  unsigned int u = (e & 0x80000000u) ? (e ^ 0x80000000u) : ~e;
  return __builtin_bit_cast(float, u);
}

#define GLOAD_LDS16(g, l)                                          \
  __builtin_amdgcn_global_load_lds(                                \
      (const __attribute__((address_space(1))) void*)(g),          \
      (__attribute__((address_space(3))) void*)(l), 16, 0, 0)

// ---------------- bf16 MFMA GEMM tile, 128x128, BK=64, 4 waves.
// XOR-swizzled LDS (slot s of row r holds col-block s^(r&7)): conflict-free
// (round-5 validated: SQ_LDS_BANK_CONFLICT = 0).
// MODE 0: write pre-BN h (bf16) + atomicAdd per-column sum/sumsq totals.
// MODE 1: no C write; per-batch column max via atomicMax(enc).
template <int MODE>
static __device__ __forceinline__ void gemm_tile(
    const unsigned short* __restrict__ A, int lda,
    const unsigned short* __restrict__ W, int ldw,
    const float* __restrict__ bias,
    unsigned short* __restrict__ Cbf, int ldc, int K,
    float* __restrict__ psum, float* __restrict__ psq,
    unsigned int* __restrict__ outenc,
    char* smem, int m0, int n0) {
  unsigned short* As = (unsigned short*)smem;          // 16384 B
  unsigned short* Bs = As + 8192;                      // 16384 B
  const int tid  = threadIdx.x;
  const int wave = tid >> 6;
  const int lane = tid & 63;

  const int srow = wave * 8 + (lane >> 3);                 // + q*32
  const int g8   = ((lane & 7) ^ ((lane >> 3) & 7)) * 8;   // swizzled global col
  const int ldst = (wave * 64 + lane) * 8;                 // + q*2048 (ushorts)

  const int quad = lane >> 4;
  const int l15  = lane & 15;
  const int wm = (wave & 1) * 64;
  const int wn = (wave >> 1) * 64;
  const int slot0 = quad ^ (l15 & 7);

  f32x4 acc[4][4];
  #pragma unroll
  for (int i = 0; i < 4; ++i)
    #pragma unroll
    for (int j = 0; j < 4; ++j)
      acc[i][j] = (f32x4)(0.0f);

  for (int k0 = 0; k0 < K; k0 += 64) {
    #pragma unroll
    for (int q = 0; q < 4; ++q) {
      GLOAD_LDS16(A + (size_t)(m0 + q * 32 + srow) * lda + k0 + g8,
                  &As[q * 2048 + ldst]);
      GLOAD_LDS16(W + (size_t)(n0 + q * 32 + srow) * ldw + k0 + g8,
                  &Bs[q * 2048 + ldst]);
    }
    __syncthreads();
    #pragma unroll
    for (int kk = 0; kk < 2; ++kk) {
      const int slot = slot0 ^ (kk * 4);
      bf16x8 af[4], bfr[4];
      #pragma unroll
      for (int i = 0; i < 4; ++i)
        af[i] = *(const bf16x8*)&As[(wm + 16 * i + l15) * 64 + slot * 8];
      #pragma unroll
      for (int j = 0; j < 4; ++j)
        bfr[j] = *(const bf16x8*)&Bs[(wn + 16 * j + l15) * 64 + slot * 8];
      #pragma unroll
      for (int i = 0; i < 4; ++i)
        #pragma unroll
        for (int j = 0; j < 4; ++j)
          acc[i][j] = __builtin_amdgcn_mfma_f32_16x16x32_bf16(af[i], bfr[j], acc[i][j], 0, 0, 0);
    }
    __syncthreads();
  }

  // epilogue: C/D layout col=lane&15, row=quad*4+reg
  if (MODE == 0) {
    float* s_sum = (float*)smem;          // aliases dead As region
    float* s_sq  = s_sum + 256;
    #pragma unroll
    for (int j = 0; j < 4; ++j) {
      int col = n0 + wn + 16 * j + l15;
      float bb = bias[col];
      float sm = 0.f, sq = 0.f;
      #pragma unroll
      for (int i = 0; i < 4; ++i) {
        int row_base = m0 + wm + 16 * i + quad * 4;
        #pragma unroll
        for (int r = 0; r < 4; ++r) {
          float v = acc[i][j][r] + bb;
          Cbf[(size_t)(row_base + r) * ldc + col] = f2bf(v);
          sm += v; sq += v * v;
        }
      }
      sm += __shfl_xor(sm, 16, 64); sm += __shfl_xor(sm, 32, 64);
      sq += __shfl_xor(sq, 16, 64); sq += __shfl_xor(sq, 32, 64);
      if (quad == 0) { s_sum[wave * 64 + j * 16 + l15] = sm;
                       s_sq [wave * 64 + j * 16 + l15] = sq; }
    }
    __syncthreads();
    if (tid < 128) {
      int half = tid >> 6;
      int c = tid & 63;
      float sm = s_sum[half * 128 + c] + s_sum[half * 128 + 64 + c];
      float sq = s_sq [half * 128 + c] + s_sq [half * 128 + 64 + c];
      int col = n0 + half * 64 + c;
      atomicAdd(&psum[col], sm);
      atomicAdd(&psq [col], sq);
    }
    __syncthreads();
  } else {
    #pragma unroll
    for (int j = 0; j < 4; ++j) {
      int col = n0 + wn + 16 * j + l15;
      float bb = bias[col];
      float m[4];
      #pragma unroll
      for (int i = 0; i < 4; ++i) {
        float v = fmaxf(fmaxf(acc[i][j][0], acc[i][j][1]),
                        fmaxf(acc[i][j][2], acc[i][j][3]));
        m[i] = v + bb;
      }
      #pragma unroll
      for (int i = 0; i < 4; ++i) {
        m[i] = fmaxf(m[i], __shfl_xor(m[i], 16, 64));
        m[i] = fmaxf(m[i], __shfl_xor(m[i], 32, 64));
      }
      if (quad == 0) {
        int base = m0 + wm;
        float cur = m[0]; int cb = base / K_;
        #pragma unroll
        for (int i = 1; i < 4; ++i) {
          int bi = (base + 16 * i) / K_;
          if (bi == cb) cur = fmaxf(cur, m[i]);
          else { atomicMax(&outenc[cb * E_ + col], encf(cur)); cur = m[i]; cb = bi; }
        }
        atomicMax(&outenc[cb * E_ + col], encf(cur));
      }
    }
  }
}

// ---------------- shared device helpers ----------------
static __device__ __forceinline__ void topk_block(
    const float* __restrict__ atten, int* __restrict__ idx, int b,
    float* s, int tid) {
  const float* row = atten + (size_t)b * L_ * L_;   // atten[b][0][:]
  for (int i = tid; i < L_; i += 256) s[i] = (i == 0) ? -1.0f : row[i];
  __syncthreads();
  for (int i = tid; i < L_; i += 256) {
    float si = s[i];
    int rank = 0;
    for (int j = 0; j < L_; ++j) {
      float sj = s[j];
      rank += (sj > si) || (sj == si && j < i);
    }
    if (rank < K_) idx[b * K_ + rank] = i;
  }
  __syncthreads();
}

static __device__ __forceinline__ void bn_coef(
    const float* psum, const float* psq, const float* gamma,
    const float* beta, float* scsh, int c) {
  const float invN = 1.0f / (float)N_;
  float mu = psum[c] * invN;
  float var = psq[c] * invN - mu * mu;
  float sc = rsqrtf(var + 1e-5f) * gamma[c];
  scsh[c] = sc;
  scsh[512 + c] = beta[c] - mu * sc;
}

// ================= cooperative mega-kernel (GRID_=576 blocks) =================
__global__ __launch_bounds__(256, 3) void mega_kernel(
    const float* __restrict__ base, const float* __restrict__ atten,
    const float* __restrict__ fc_w, const float* __restrict__ fc_b,
    const float* __restrict__ w0,   const float* __restrict__ b0,
    const float* __restrict__ gamma, const float* __restrict__ beta,
    const float* __restrict__ w1,   const float* __restrict__ b1,
    float* __restrict__ out, char* __restrict__ ws) {
  __shared__ __align__(16) char smem[32768];
  cg::grid_group grid = cg::this_grid();

  unsigned short* wbig    = (unsigned short*)(ws + OFF_WBIG);
  unsigned short* w0b     = (unsigned short*)(ws + OFF_W0B);
  float*          biasbig = (float*)(ws + OFF_BIASBIG);
  float*          scsh    = (float*)(ws + OFF_SCSH);
  int*            idx     = (int*)  (ws + OFF_IDX);
  float*          psum    = (float*)(ws + OFF_PSUM);
  float*          psq     = (float*)(ws + OFF_PSQ);
  unsigned int*   outenc  = (unsigned int*)(ws + OFF_OUTENC);
  unsigned short* abig    = (unsigned short*)(ws + OFF_ABIG);

  const int blk = blockIdx.x;
  const int tid = threadIdx.x;

  // ===== P0: pack weights (bf16), biases, zero accumulators; top-k =====
  for (int gid = blk * 256 + tid; gid < 327680; gid += NTHREADS) {
    if (gid < 65536) outenc[gid] = 0u;
    if (gid < 512) { psum[gid] = 0.f; psq[gid] = 0.f; }
    if (gid < E_) biasbig[gid] = fc_b[gid] + b1[gid];
    if (gid < 262144) {                      // wbig: 1024 rows x 256 f4-cols
      int e  = gid >> 8;
      int c4 = gid & 255;
      float4 v;
      if (c4 < 128) v = ((const float4*)(fc_w + e * D_))[c4];
      else          v = ((const float4*)(w1   + e * H_))[c4 - 128];
      ushort4v o = { f2bf(v.x), f2bf(v.y), f2bf(v.z), f2bf(v.w) };
      ((ushort4v*)wbig)[gid] = o;
    } else {                                 // w0b: 512x512
      int i2 = gid - 262144;
      float4 v = ((const float4*)w0)[i2];
      ushort4v o = { f2bf(v.x), f2bf(v.y), f2bf(v.z), f2bf(v.w) };
      ((ushort4v*)w0b)[i2] = o;
    }
  }
  if (blk >= GRID_ - B_) topk_block(atten, idx, blk - (GRID_ - B_), (float*)smem, tid);
  __threadfence();
  grid.sync();

  // ===== P1: gather + l2norm -> abig[:,0:512] (32 rows per block) =====
  {
    float* gw = (float*)smem;                // [4] per-wave sums
    const int half = tid >> 7;
    const int t128 = tid & 127;
    const int wv   = tid >> 6;
    for (int it = 0; it < 16; ++it) {
      int r = blk * 32 + it * 2 + half;
      int b = r / K_;
      int tok = idx[r];
      const float* src = base + ((size_t)b * L_ + tok) * D_;
      float4 v = ((const float4*)src)[t128];
      float ss = v.x * v.x + v.y * v.y + v.z * v.z + v.w * v.w;
      #pragma unroll
      for (int o = 32; o > 0; o >>= 1) ss += __shfl_down(ss, o, 64);
      if ((tid & 63) == 0) gw[wv] = ss;
      __syncthreads();
      float total = gw[2 * half] + gw[2 * half + 1];
      float inv = 1.0f / (sqrtf(total) + 1e-8f);
      ushort4v o4 = { f2bf(v.x * inv), f2bf(v.y * inv),
                      f2bf(v.z * inv), f2bf(v.w * inv) };
      ((ushort4v*)(abig + (size_t)r * KBIG))[t128] = o4;
      __syncthreads();
    }
  }
  __threadfence();
  grid.sync();

  // ===== P2: GEMM1 h = feats @ w0^T + b0 -> abig[:,512:1024] + BN totals =====
  {
    int m0 = (blk % MTILES) * 128;
    int n0 = (blk / MTILES) * 128;
    gemm_tile<0>(abig, KBIG, w0b, D_, b0, abig + H_, KBIG, D_,
                 psum, psq, nullptr, smem, m0, n0);
  }
  __threadfence();
  grid.sync();

  // ===== P3: BN scale/shift from totals =====
  if (blk == 0)
    for (int c = tid; c < H_; c += 256) bn_coef(psum, psq, gamma, beta, scsh, c);
  __threadfence();
  grid.sync();

  // ===== P4: BN apply + ReLU in place (bf16) =====
  for (int gid = blk * 256 + tid; gid < N_ * 64; gid += NTHREADS) {
    int r = gid >> 6;
    int c8 = gid & 63;
    int c = c8 * 8;
    ushort8v* p = (ushort8v*)(abig + (size_t)r * KBIG + H_) + c8;
    ushort8v v = *p;
    ushort8v o;
    #pragma unroll
    for (int j = 0; j < 8; ++j) {
      float x = bf2f(v[j]);
      o[j] = f2bf(fmaxf(x * scsh[c + j] + scsh[512 + c + j], 0.0f));
    }
    *p = o;
  }
  __threadfence();
  grid.sync();

  // ===== P5: GEMM2 + fused per-batch column max (2 tiles/block, same m0) =====
  for (int t = blk; t < MTILES * 8; t += GRID_) {
    int m0 = (t % MTILES) * 128;
    int n0 = (t / MTILES) * 128;
    gemm_tile<1>(abig, KBIG, wbig, KBIG, biasbig, nullptr, 0, KBIG,
                 nullptr, nullptr, outenc, smem, m0, n0);
  }
  __threadfence();
  grid.sync();

  // ===== P6: decode -> out =====
  for (int gid = blk * 256 + tid; gid < B_ * E_; gid += NTHREADS)
    out[gid] = decf(outenc[gid]);
}

// ================= fallback multi-kernel path (round-5 proven) =================
__global__ __launch_bounds__(256) void prep_kernel(
    const float* __restrict__ fc_w, const float* __restrict__ fc_b,
    const float* __restrict__ w0,   const float* __restrict__ w1,
    const float* __restrict__ b1,
    unsigned short* __restrict__ wbig, unsigned short* __restrict__ w0b,
    float* __restrict__ biasbig, unsigned int* __restrict__ outenc,
    float* __restrict__ psum, float* __restrict__ psq) {
  int gid = blockIdx.x * 256 + threadIdx.x;      // 327680 total
  if (gid < 65536) outenc[gid] = 0u;
  if (gid < 512) { psum[gid] = 0.f; psq[gid] = 0.f; }
  if (gid < E_) biasbig[gid] = fc_b[gid] + b1[gid];
  if (gid < 262144) {
    int e  = gid >> 8;
    int c4 = gid & 255;
    float4 v;
    if (c4 < 128) v = ((const float4*)(fc_w + e * D_))[c4];
    else          v = ((const float4*)(w1   + e * H_))[c4 - 128];
    ushort4v o = { f2bf(v.x), f2bf(v.y), f2bf(v.z), f2bf(v.w) };
    ((ushort4v*)wbig)[gid] = o;
  } else {
    int i2 = gid - 262144;
    float4 v = ((const float4*)w0)[i2];
    ushort4v o = { f2bf(v.x), f2bf(v.y), f2bf(v.z), f2bf(v.w) };
    ((ushort4v*)w0b)[i2] = o;
  }
}

__global__ __launch_bounds__(256) void topk_kernel(
    const float* __restrict__ atten, int* __restrict__ idx) {
  __shared__ float s[L_];
  topk_block(atten, idx, blockIdx.x, s, threadIdx.x);
}

__global__ __launch_bounds__(128) void gather_norm_kernel(
    const float* __restrict__ base, const int* __restrict__ idx,
    unsigned short* __restrict__ abig) {
  int r = blockIdx.x;
  int b = r / K_;
  int tok = idx[r];
  const float* src = base + ((size_t)b * L_ + tok) * D_;
  float4 v = ((const float4*)src)[threadIdx.x];
  float ss = v.x * v.x + v.y * v.y + v.z * v.z + v.w * v.w;
  #pragma unroll
  for (int o = 32; o > 0; o >>= 1) ss += __shfl_down(ss, o, 64);
  __shared__ float wsum[2];
  if ((threadIdx.x & 63) == 0) wsum[threadIdx.x >> 6] = ss;
  __syncthreads();
  float total = wsum[0] + wsum[1];
  float inv = 1.0f / (sqrtf(total) + 1e-8f);
  ushort4v o4 = { f2bf(v.x * inv), f2bf(v.y * inv), f2bf(v.z * inv), f2bf(v.w * inv) };
  ((ushort4v*)(abig + (size_t)r * KBIG))[threadIdx.x] = o4;
}

__global__ __launch_bounds__(256) void gemm0_kernel(
    unsigned short* __restrict__ abig, const unsigned short* __restrict__ w0b,
    const float* __restrict__ b0, float* __restrict__ psum,
    float* __restrict__ psq) {
  __shared__ __align__(16) char smem[32768];
  gemm_tile<0>(abig, KBIG, w0b, D_, b0, abig + H_, KBIG, D_,
               psum, psq, nullptr, smem, blockIdx.x * 128, blockIdx.y * 128);
}

__global__ __launch_bounds__(256) void bn_stats2_kernel(
    const float* __restrict__ psum, const float* __restrict__ psq,
    const float* __restrict__ gamma, const float* __restrict__ beta,
    float* __restrict__ scsh) {
  int c = blockIdx.x * 256 + threadIdx.x;    // 512 threads
  bn_coef(psum, psq, gamma, beta, scsh, c);
}

__global__ __launch_bounds__(256) void bn_apply_kernel(
    unsigned short* __restrict__ abig, const float* __restrict__ scsh) {
  int gid = blockIdx.x * 256 + threadIdx.x;
  int r = gid >> 6;
  int c8 = gid & 63;
  int c = c8 * 8;
  ushort8v* p = (ushort8v*)(abig + (size_t)r * KBIG + H_) + c8;
  ushort8v v = *p;
  ushort8v o;
  #pragma unroll
  for (int j = 0; j < 8; ++j)
    o[j] = f2bf(fmaxf(bf2f(v[j]) * scsh[c + j] + scsh[512 + c + j], 0.0f));
  *p = o;
}

__global__ __launch_bounds__(256) void gemm1_kernel(
    const unsigned short* __restrict__ abig,
    const unsigned short* __restrict__ wbig,
    const float* __restrict__ biasbig, unsigned int* __restrict__ outenc) {
  __shared__ __align__(16) char smem[32768];
  gemm_tile<1>(abig, KBIG, wbig, KBIG, biasbig, nullptr, 0, KBIG,
               nullptr, nullptr, outenc, smem, blockIdx.x * 128, blockIdx.y * 128);
}

__global__ __launch_bounds__(256) void decode_kernel(
    const unsigned int* __restrict__ outenc, float* __restrict__ out) {
  int gid = blockIdx.x * 256 + threadIdx.x;
  out[gid] = decf(outenc[gid]);
}

extern "C" void kernel_launch(void* const* d_in, const int* in_sizes, int n_in,
                              void* d_out, int out_size, void* d_ws, size_t ws_size,
                              hipStream_t stream) {
  const float* base  = (const float*)d_in[0];   // [64,577,512]
  const float* atten = (const float*)d_in[1];   // [64,577,577]
  const float* fc_w  = (const float*)d_in[2];   // [1024,512]
  const float* fc_b  = (const float*)d_in[3];   // [1024]
  const float* w0    = (const float*)d_in[4];   // [512,512]
  const float* b0    = (const float*)d_in[5];   // [512]
  const float* gamma = (const float*)d_in[6];   // [512]
  const float* beta  = (const float*)d_in[7];   // [512]
  const float* w1    = (const float*)d_in[8];   // [1024,512]
  const float* b1    = (const float*)d_in[9];   // [1024]
  float* out = (float*)d_out;
  char* ws = (char*)d_ws;

  void* args[] = {
    (void*)&base, (void*)&atten, (void*)&fc_w, (void*)&fc_b,
    (void*)&w0, (void*)&b0, (void*)&gamma, (void*)&beta,
    (void*)&w1, (void*)&b1, (void*)&out, (void*)&ws,
  };
  hipError_t err = hipLaunchCooperativeKernel((const void*)mega_kernel,
                                              dim3(GRID_), dim3(256), args, 0,
                                              stream);
  if (err != hipSuccess) {
    (void)hipGetLastError();   // clear sticky error; run proven fallback
    unsigned short* wbig    = (unsigned short*)(ws + OFF_WBIG);
    unsigned short* w0b     = (unsigned short*)(ws + OFF_W0B);
    float*          biasbig = (float*)(ws + OFF_BIASBIG);
    float*          scsh    = (float*)(ws + OFF_SCSH);
    int*            idx     = (int*)  (ws + OFF_IDX);
    float*          psum    = (float*)(ws + OFF_PSUM);
    float*          psq     = (float*)(ws + OFF_PSQ);
    unsigned int*   outenc  = (unsigned int*)(ws + OFF_OUTENC);
    unsigned short* abig    = (unsigned short*)(ws + OFF_ABIG);

    prep_kernel<<<1280, 256, 0, stream>>>(fc_w, fc_b, w0, w1, b1, wbig, w0b,
                                          biasbig, outenc, psum, psq);
    topk_kernel<<<B_, 256, 0, stream>>>(atten, idx);
    gather_norm_kernel<<<N_, 128, 0, stream>>>(base, idx, abig);
    gemm0_kernel<<<dim3(MTILES, H_ / 128), 256, 0, stream>>>(abig, w0b, b0,
                                                             psum, psq);
    bn_stats2_kernel<<<2, 256, 0, stream>>>(psum, psq, gamma, beta, scsh);
    bn_apply_kernel<<<(N_ * 64) / 256, 256, 0, stream>>>(abig, scsh);
    gemm1_kernel<<<dim3(MTILES, E_ / 128), 256, 0, stream>>>(abig, wbig,
                                                             biasbig, outenc);
    decode_kernel<<<(B_ * E_) / 256, 256, 0, stream>>>(outenc, out);
  }
}